// Round 2
// baseline (236.264 us; speedup 1.0000x reference)
//
#include <hip/hip_runtime.h>

// Problem constants (fixed by setup_inputs)
#define BB 8
#define TC 1024
#define EE 256
#define KJ 8
#define MSEL 2048
#define V1 17          // V+1
#define T1 8192        // TC*KJ
#define TTOT 24576     // T1 + M*K
#define BI_TOT 16384   // BB*MSEL
#define NCOL 136       // KJ*V1
#define NCOLP 144      // KJ*18 (v padded to 18)

// Workspace layout (bytes)
#define SCAL_OFF 0                         // 32 ints: [0]=maxdepth [1..8]=len1 [9..16]=mix1 [17..24]=cnt
#define SEL_OFF  1024                      // 16384 ints
#define GRP_OFF  (SEL_OFF + 65536)         // 8*16384 ints
#define WF_OFF   (GRP_OFF + 524288)        // Wfused PADDED [e][j*18+v]: 256*144 f32
#define B2_OFF   (WF_OFF + 147456)         // bias2 [j][v]: 136 f32
#define BF0_OFF  (B2_OFF + 1024)           // bfused0: 17 f32
#define WC_OFF   (BF0_OFF + 1024)          // Wcomb [g][e][col=j*18+v]: 8*256*144 f32

__global__ __launch_bounds__(256) void k_maxdepth(const int* depth, int* scal) {
    int idx = blockIdx.x * 256 + threadIdx.x;
    int v = depth[idx];
    #pragma unroll
    for (int d = 32; d; d >>= 1) v = max(v, __shfl_down(v, d, 64));
    __shared__ int sm[4];
    int lane = threadIdx.x & 63, wid = threadIdx.x >> 6;
    if (lane == 0) sm[wid] = v;
    __syncthreads();
    if (threadIdx.x == 0) atomicMax(&scal[0], max(max(sm[0], sm[1]), max(sm[2], sm[3])));
}

__global__ __launch_bounds__(256) void k_len1(const int* depth, int* scal) {
    int idx = blockIdx.x * 256 + threadIdx.x;
    int b = idx / TTOT;                    // uniform per block (TTOT % 256 == 0)
    int md = scal[0];
    unsigned long long bal = __ballot(depth[idx] == md - 1);
    __shared__ int sm[4];
    int lane = threadIdx.x & 63, wid = threadIdx.x >> 6;
    if (lane == 0) sm[wid] = __popcll(bal);
    __syncthreads();
    if (threadIdx.x == 0) {
        int t = sm[0] + sm[1] + sm[2] + sm[3];
        if (t) atomicAdd(&scal[1 + b], t);
    }
}

// One block per batch: stable compaction of first MSEL positions with value==2 (t<len1)
__global__ __launch_bounds__(256) void k_scan(const int* value, int* scal, int* sel) {
    int b = blockIdx.x, tid = threadIdx.x;
    int len1 = scal[1 + b];
    const int* vb = value + b * TTOT;
    int t0 = tid * 32;                      // thread owns contiguous [t0, t0+32)
    unsigned mask = 0;
    #pragma unroll
    for (int k = 0; k < 32; k += 4) {
        int4 v = *(const int4*)(vb + t0 + k);
        if (t0 + k + 0 < len1 && v.x == 2) mask |= 1u << (k + 0);
        if (t0 + k + 1 < len1 && v.y == 2) mask |= 1u << (k + 1);
        if (t0 + k + 2 < len1 && v.z == 2) mask |= 1u << (k + 2);
        if (t0 + k + 3 < len1 && v.w == 2) mask |= 1u << (k + 3);
    }
    int cnt = __popc(mask);
    int inc = cnt;
    #pragma unroll
    for (int d = 1; d < 64; d <<= 1) {
        int n = __shfl_up(inc, d, 64);
        if ((tid & 63) >= d) inc += n;
    }
    __shared__ int wt[4];
    int lane = tid & 63, wid = tid >> 6;
    if (lane == 63) wt[wid] = inc;
    __syncthreads();
    int woff = 0;
    for (int w = 0; w < wid; ++w) woff += wt[w];
    int off = woff + inc - cnt;
    #pragma unroll
    for (int k = 0; k < 32; ++k) {
        if (mask & (1u << k)) {
            if (off < MSEL) sel[b * MSEL + off] = t0 + k;
            off++;
        }
    }
    if (tid == 0) scal[9 + b] = wt[0] + wt[1] + wt[2] + wt[3];   // mix_1[b]
}

// Bin (b,i) entries by jsel = sel%8
__global__ __launch_bounds__(256) void k_group(const int* sel, int* scal, int* groups) {
    __shared__ int lcnt[KJ], lbase[KJ];
    if (threadIdx.x < KJ) lcnt[threadIdx.x] = 0;
    __syncthreads();
    int idx = blockIdx.x * 256 + threadIdx.x;          // = b*MSEL + i
    int b = idx >> 11, i = idx & (MSEL - 1);
    int valid = (i < scal[9 + b]) ? 1 : 0;
    int t = valid ? sel[idx] : 0;
    int g = t & 7, tq = t >> 3;
    int lslot = atomicAdd(&lcnt[g], 1);
    __syncthreads();
    if (threadIdx.x < KJ) lbase[threadIdx.x] = atomicAdd(&scal[17 + threadIdx.x], lcnt[threadIdx.x]);
    __syncthreads();
    groups[g * BI_TOT + lbase[g] + lslot] = (idx << 11) | (tq << 1) | valid;
}

// Wfused[e][j*18+v] (padded) = sum_o W0[e,o,j] * Wl[v,o]
__global__ __launch_bounds__(256) void k_wfused(const float* W0, const float* Wl, float* wf) {
    int e = blockIdx.x;
    __shared__ float w0s[EE * KJ];
    __shared__ float wls[V1 * 257];          // stride 257: conflict-free
    for (int idx = threadIdx.x; idx < EE * KJ; idx += 256) w0s[idx] = W0[e * EE * KJ + idx];
    for (int idx = threadIdx.x; idx < V1 * EE; idx += 256) {
        int v = idx >> 8, o = idx & 255;
        wls[v * 257 + o] = Wl[idx];
    }
    __syncthreads();
    int tid = threadIdx.x;
    if (tid < NCOL) {
        int j = tid / V1, v = tid - j * V1;
        float acc = 0.f;
        for (int o = 0; o < EE; ++o) acc += w0s[o * KJ + j] * wls[v * 257 + o];
        wf[e * NCOLP + j * 18 + v] = acc;
    }
    if (tid < KJ) wf[e * NCOLP + tid * 18 + 17] = 0.f;   // pad cols
}

// bfused0[v] = b0·Wl[v,:] + bl[v];  bias2[j*17+v] = sum_e b1[e]*Wfused[e][j][v] + bfused0[v]
__global__ __launch_bounds__(256) void k_bias(const float* b0, const float* bl, const float* b1,
                                              const float* Wl, const float* wf,
                                              float* bias2, float* bf0) {
    int tid = threadIdx.x;
    __shared__ float bf0s[V1];
    if (tid < V1) {
        float a = bl[tid];
        for (int o = 0; o < EE; ++o) a += b0[o] * Wl[tid * EE + o];
        bf0[tid] = a; bf0s[tid] = a;
    }
    __syncthreads();
    if (tid < NCOL) {
        int j = tid / V1, v = tid - j * V1;
        float a = 0.f;
        for (int e = 0; e < EE; ++e) a += b1[e] * wf[e * NCOLP + j * 18 + v];
        bias2[tid] = a + bf0s[v];
    }
}

// Wcomb[g][e][col] = sum_em W1[e,em,g] * Wfused[em][col]   (tiled GEMM, coalesced W1 staging)
// grid: 8 g x 8 e-tiles(32) = 64 blocks, 512 threads
__global__ __launch_bounds__(512) void k_wcomb(const float* W1, const float* wf, float* wc) {
    int g = blockIdx.x >> 3;
    int e0 = (blockIdx.x & 7) * 32;
    __shared__ float a1s[64 * 33];           // [em-local][e-local], stride 33 conflict-free
    __shared__ float wfs[64 * NCOLP];        // [em-local][col]
    int tid = threadIdx.x;
    int tx = tid & 31;                        // e-row (1 each)
    int ty = tid >> 5;                        // 0..15: cols ty+16c
    float acc[9];
    #pragma unroll
    for (int c = 0; c < 9; ++c) acc[c] = 0.f;

    for (int ch = 0; ch < 4; ++ch) {
        __syncthreads();
        int em0 = ch * 64;
        {   // stage A chunk: lanes consecutive in em -> 32B-stride coalesced-ish
            int emi = tid & 63, er = tid >> 6;    // er 0..7
            #pragma unroll
            for (int i = 0; i < 4; ++i) {
                int e = er * 4 + i;
                a1s[emi * 33 + e] = W1[((e0 + e) * EE + em0 + emi) * KJ + g];
            }
        }
        {   // stage B chunk: pure float4 copy (wf is pre-padded to 144)
            const float4* src = (const float4*)(wf + em0 * NCOLP);
            #pragma unroll
            for (int p = 0; p < 5; ++p) {
                int idx = tid + p * 512;
                if (idx < 64 * NCOLP / 4) ((float4*)wfs)[idx] = src[idx];
            }
        }
        __syncthreads();
        #pragma unroll 4
        for (int em = 0; em < 64; ++em) {
            float a = a1s[em * 33 + tx];
            #pragma unroll
            for (int c = 0; c < 9; ++c) acc[c] += a * wfs[em * NCOLP + ty + 16 * c];
        }
    }
    float* outp = wc + (g * EE + e0 + tx) * NCOLP;
    #pragma unroll
    for (int c = 0; c < 9; ++c) outp[ty + 16 * c] = acc[c];
}

// Main grouped GEMM: per block (g, 64-row tile): C[64 x 144] = X[64 x 256] * Wcomb_g[256 x 144]
// 512 threads (8 waves -> 2 waves/SIMD), LDS double-buffered, 1 barrier/chunk
__global__ __launch_bounds__(512) void k_main(const float* x, const float* wc, const int* scal,
                                              const int* groups, const float* bias2,
                                              const float* bf0, float* out) {
    int g = blockIdx.x >> 6;
    int tile = blockIdx.x & 63;
    int cntg = scal[17 + g];
    if (tile * 64 >= cntg) return;
    int nrows = min(64, cntg - tile * 64);

    __shared__ float xs[2][64 * 69];         // [buf][row][e] pad 69
    __shared__ float wsm[2][64 * NCOLP];     // [buf][e][col]
    __shared__ int xoffs[64];
    __shared__ int obase[64];
    __shared__ unsigned char vflag[64];      // 0=no row, 1=invalid (bias only), 2=valid

    int tid = threadIdx.x;
    if (tid < 64) {
        int flag = 0, xo = 0, ob = 0;
        if (tid < nrows) {
            int p = groups[g * BI_TOT + tile * 64 + tid];
            int valid = p & 1;
            int tq = (p >> 1) & 1023;
            int bi = p >> 11;
            int b = bi >> 11;
            xo = (b * TC + tq) * EE;
            ob = bi * NCOL;                  // ((b*16384)+(i*8))*17
            flag = 1 + valid;
        }
        xoffs[tid] = xo; obase[tid] = ob; vflag[tid] = (unsigned char)flag;
    }
    __syncthreads();

    int qx = tid & 15, rx = tid >> 4;        // x staging: rows rx, rx+32; float4 qx
    const float4* wsrc = (const float4*)(wc + g * EE * NCOLP);

    {   // stage chunk 0 directly
        float4 v0 = *(const float4*)(x + xoffs[rx] + qx * 4);
        float4 v1 = *(const float4*)(x + xoffs[rx + 32] + qx * 4);
        float* d0 = &xs[0][rx * 69 + qx * 4];
        d0[0] = v0.x; d0[1] = v0.y; d0[2] = v0.z; d0[3] = v0.w;
        float* d1 = &xs[0][(rx + 32) * 69 + qx * 4];
        d1[0] = v1.x; d1[1] = v1.y; d1[2] = v1.z; d1[3] = v1.w;
        #pragma unroll
        for (int p = 0; p < 5; ++p) {
            int idx = tid + p * 512;
            if (idx < 2304) ((float4*)wsm[0])[idx] = wsrc[idx];
        }
    }
    __syncthreads();

    int tx = tid & 31;      // rows tx*2, tx*2+1
    int ty = tid >> 5;      // cols ty + 16*c

    float acc0[9], acc1[9];
    #pragma unroll
    for (int c = 0; c < 9; ++c) { acc0[c] = 0.f; acc1[c] = 0.f; }

    for (int ch = 0; ch < 4; ++ch) {
        int cur = ch & 1;
        float4 px0, px1, pw[5];
        if (ch < 3) {   // prefetch next chunk into registers
            px0 = *(const float4*)(x + xoffs[rx] + (ch + 1) * 64 + qx * 4);
            px1 = *(const float4*)(x + xoffs[rx + 32] + (ch + 1) * 64 + qx * 4);
            #pragma unroll
            for (int p = 0; p < 5; ++p) {
                int idx = tid + p * 512;
                if (idx < 2304) pw[p] = wsrc[(ch + 1) * 2304 + idx];
            }
        }
        #pragma unroll 2
        for (int e = 0; e < 64; ++e) {
            float xv0 = xs[cur][(tx * 2 + 0) * 69 + e];
            float xv1 = xs[cur][(tx * 2 + 1) * 69 + e];
            #pragma unroll
            for (int c = 0; c < 9; ++c) {
                float wv = wsm[cur][e * NCOLP + ty + 16 * c];
                acc0[c] += xv0 * wv;
                acc1[c] += xv1 * wv;
            }
        }
        if (ch < 3) {   // write prefetched regs to the other buffer
            int nxt = cur ^ 1;
            float* d0 = &xs[nxt][rx * 69 + qx * 4];
            d0[0] = px0.x; d0[1] = px0.y; d0[2] = px0.z; d0[3] = px0.w;
            float* d1 = &xs[nxt][(rx + 32) * 69 + qx * 4];
            d1[0] = px1.x; d1[1] = px1.y; d1[2] = px1.z; d1[3] = px1.w;
            #pragma unroll
            for (int p = 0; p < 5; ++p) {
                int idx = tid + p * 512;
                if (idx < 2304) ((float4*)wsm[nxt])[idx] = pw[p];
            }
        }
        __syncthreads();
    }

    #pragma unroll
    for (int c = 0; c < 9; ++c) {
        int col = ty + 16 * c;
        int j = col / 18;
        int v = col - j * 18;
        if (v < V1) {
            float bias = bias2[j * V1 + v];
            float b0v = bf0[v];
            int row0 = tx * 2, row1 = tx * 2 + 1;
            int f0 = vflag[row0], f1 = vflag[row1];
            if (f0) out[obase[row0] + j * V1 + v] = (f0 == 2) ? (acc0[c] + bias) : b0v;
            if (f1) out[obase[row1] + j * V1 + v] = (f1 == 2) ? (acc1[c] + bias) : b0v;
        }
    }
}

extern "C" void kernel_launch(void* const* d_in, const int* in_sizes, int n_in,
                              void* d_out, int out_size, void* d_ws, size_t ws_size,
                              hipStream_t stream) {
    const float* x     = (const float*)d_in[0];
    const int*   value = (const int*)d_in[1];
    const int*   depth = (const int*)d_in[2];
    // d_in[3] = pos (unused), d_in[4] = num_mix (constant 2048)
    const float* W1    = (const float*)d_in[5];
    const float* b1    = (const float*)d_in[6];
    const float* W0    = (const float*)d_in[7];
    const float* b0    = (const float*)d_in[8];
    const float* Wl    = (const float*)d_in[9];
    const float* bl    = (const float*)d_in[10];
    float* out = (float*)d_out;
    char* ws = (char*)d_ws;

    int*   scal   = (int*)(ws + SCAL_OFF);
    int*   sel    = (int*)(ws + SEL_OFF);
    int*   groups = (int*)(ws + GRP_OFF);
    float* wf     = (float*)(ws + WF_OFF);
    float* bias2  = (float*)(ws + B2_OFF);
    float* bf0    = (float*)(ws + BF0_OFF);
    float* wc     = (float*)(ws + WC_OFF);

    hipMemsetAsync(scal, 0, 128, stream);
    k_maxdepth<<<dim3((BB * TTOT) / 256), dim3(256), 0, stream>>>(depth, scal);
    k_len1    <<<dim3((BB * TTOT) / 256), dim3(256), 0, stream>>>(depth, scal);
    k_scan    <<<dim3(BB),   dim3(256), 0, stream>>>(value, scal, sel);
    k_group   <<<dim3(64),   dim3(256), 0, stream>>>(sel, scal, groups);
    k_wfused  <<<dim3(EE),   dim3(256), 0, stream>>>(W0, Wl, wf);
    k_bias    <<<dim3(1),    dim3(256), 0, stream>>>(b0, bl, b1, Wl, wf, bias2, bf0);
    k_wcomb   <<<dim3(64),   dim3(512), 0, stream>>>(W1, wf, wc);
    k_main    <<<dim3(512),  dim3(512), 0, stream>>>(x, wc, scal, groups, bias2, bf0, out);
}

// Round 3
// 129.569 us; speedup vs baseline: 1.8235x; 1.8235x over previous
//
#include <hip/hip_runtime.h>

typedef __attribute__((ext_vector_type(8))) short bf16x8;   // 8 bf16 = 4 VGPR
typedef __attribute__((ext_vector_type(4))) float f32x4;    // MFMA acc

// Problem constants (fixed by setup_inputs)
#define BB 8
#define TC 1024
#define EE 256
#define KJ 8
#define MSEL 2048
#define V1 17
#define T1 8192
#define TTOT 24576
#define BI_TOT 16384
#define NCOLP 160        // 8 j-groups * 20 (v padded 17->20 for even wave split)
#define WSTRIDE 264      // K-dim stride in bf16 elems (256 + 8, 16B-aligned rows)

// Workspace layout (bytes)
#define SCAL_OFF 0                          // ints: [0]=maxdepth [1..8]=len1 [9..16]=mix1 [17..24]=cnt
#define SEL_OFF  1024                       // 16384 ints
#define GRP_OFF  (SEL_OFF + 65536)          // 8*16384 ints
#define WFT_OFF  (GRP_OFF + 524288)         // wfT bf16 [160][264]
#define B2_OFF   (WFT_OFF + NCOLP*WSTRIDE*2)// bias2P f32 [160] (excl bf0)
#define BF0_OFF  (B2_OFF + 640)             // bf0 f32 [17]
#define WCT_OFF  (BF0_OFF + 128)            // wct bf16 [8][160][264]  (WcombT: [g][col][e])

__device__ __forceinline__ unsigned short f2bf(float f) {   // RTNE
    union { float f; unsigned u; } x; x.f = f;
    unsigned r = x.u + 0x7fffu + ((x.u >> 16) & 1u);
    return (unsigned short)(r >> 16);
}
__device__ __forceinline__ float bf2f(unsigned short h) {
    union { unsigned u; float f; } x; x.u = ((unsigned)h) << 16;
    return x.f;
}

__device__ __forceinline__ float blockReduceSum256(float v) {
    #pragma unroll
    for (int d = 32; d; d >>= 1) v += __shfl_down(v, d, 64);
    __shared__ float sm[4];
    int lane = threadIdx.x & 63, wid = threadIdx.x >> 6;
    if (lane == 0) sm[wid] = v;
    __syncthreads();
    return sm[0] + sm[1] + sm[2] + sm[3];
}

// 192 blocks: int4 over depth; also zeroes scal[1..31] (block 0).
// scal[0] init relies on documented 0xAA poison (negative as signed int) -> atomicMax correct.
__global__ __launch_bounds__(256) void k_maxdepth(const int* depth, int* scal) {
    int idx = blockIdx.x * 256 + threadIdx.x;
    int4 d = ((const int4*)depth)[idx];
    int v = max(max(d.x, d.y), max(d.z, d.w));
    #pragma unroll
    for (int dd = 32; dd; dd >>= 1) v = max(v, __shfl_down(v, dd, 64));
    __shared__ int sm[4];
    int lane = threadIdx.x & 63, wid = threadIdx.x >> 6;
    if (lane == 0) sm[wid] = v;
    __syncthreads();
    if (threadIdx.x == 0) atomicMax(&scal[0], max(max(sm[0], sm[1]), max(sm[2], sm[3])));
    if (blockIdx.x == 0 && threadIdx.x < 31) scal[1 + threadIdx.x] = 0;
}

// 192 blocks: count depth==maxdepth-1 per batch (each block within one b: 24 blocks/b)
__global__ __launch_bounds__(256) void k_len1(const int* depth, int* scal) {
    int idx = blockIdx.x * 256 + threadIdx.x;
    int b = blockIdx.x / 24;
    int md1 = scal[0] - 1;
    int4 d = ((const int4*)depth)[idx];
    int c = (d.x == md1) + (d.y == md1) + (d.z == md1) + (d.w == md1);
    #pragma unroll
    for (int dd = 32; dd; dd >>= 1) c += __shfl_down(c, dd, 64);
    __shared__ int sm[4];
    int lane = threadIdx.x & 63, wid = threadIdx.x >> 6;
    if (lane == 0) sm[wid] = c;
    __syncthreads();
    if (threadIdx.x == 0) {
        int t = sm[0] + sm[1] + sm[2] + sm[3];
        if (t) atomicAdd(&scal[1 + b], t);
    }
}

// One block per batch: stable compaction of first MSEL positions with value==2 (t<len1)
__global__ __launch_bounds__(256) void k_scan(const int* value, int* scal, int* sel) {
    int b = blockIdx.x, tid = threadIdx.x;
    int len1 = scal[1 + b];
    const int* vb = value + b * TTOT;
    int t0 = tid * 32;
    unsigned mask = 0;
    #pragma unroll
    for (int k = 0; k < 32; k += 4) {
        int4 v = *(const int4*)(vb + t0 + k);
        if (t0 + k + 0 < len1 && v.x == 2) mask |= 1u << (k + 0);
        if (t0 + k + 1 < len1 && v.y == 2) mask |= 1u << (k + 1);
        if (t0 + k + 2 < len1 && v.z == 2) mask |= 1u << (k + 2);
        if (t0 + k + 3 < len1 && v.w == 2) mask |= 1u << (k + 3);
    }
    int cnt = __popc(mask);
    int inc = cnt;
    #pragma unroll
    for (int d = 1; d < 64; d <<= 1) {
        int n = __shfl_up(inc, d, 64);
        if ((tid & 63) >= d) inc += n;
    }
    __shared__ int wt[4];
    int lane = tid & 63, wid = tid >> 6;
    if (lane == 63) wt[wid] = inc;
    __syncthreads();
    int woff = 0;
    for (int w = 0; w < wid; ++w) woff += wt[w];
    int off = woff + inc - cnt;
    #pragma unroll
    for (int k = 0; k < 32; ++k) {
        if (mask & (1u << k)) {
            if (off < MSEL) sel[b * MSEL + off] = t0 + k;
            off++;
        }
    }
    if (tid == 0) scal[9 + b] = wt[0] + wt[1] + wt[2] + wt[3];   // mix_1[b]
}

// wfT[colP=j*20+v][em] = bf16( sum_o W0[em,o,j] * Wl[v,o] );  256 blocks (one per em)
__global__ __launch_bounds__(256) void k_wfused(const float* W0, const float* Wl, unsigned short* wfT) {
    int em = blockIdx.x;
    __shared__ float w0s[EE * KJ];
    __shared__ float wls[V1 * 257];
    for (int idx = threadIdx.x; idx < EE * KJ; idx += 256) w0s[idx] = W0[em * EE * KJ + idx];
    for (int idx = threadIdx.x; idx < V1 * EE; idx += 256) {
        int v = idx >> 8, o = idx & 255;
        wls[v * 257 + o] = Wl[idx];
    }
    __syncthreads();
    int tid = threadIdx.x;
    if (tid < 136) {
        int j = tid / V1, v = tid - j * V1;
        float acc = 0.f;
        #pragma unroll 4
        for (int o = 0; o < EE; ++o) acc += w0s[o * KJ + j] * wls[v * 257 + o];
        wfT[(j * 20 + v) * WSTRIDE + em] = f2bf(acc);
    }
}

// Fused: blocks 0..63 = grouping (bin by jsel); 64..80 = bf0[v]; 81..216 = bias2P[col]
__global__ __launch_bounds__(256) void k_grpbias(const int* sel, int* scal, int* groups,
        const float* b0, const float* bl, const float* b1, const float* Wl,
        const unsigned short* wfT, float* bias2, float* bf0) {
    int bid = blockIdx.x, tid = threadIdx.x;
    if (bid < 64) {
        __shared__ int lcnt[KJ], lbase[KJ];
        if (tid < KJ) lcnt[tid] = 0;
        __syncthreads();
        int idx = bid * 256 + tid;                  // = b*MSEL + i
        int b = idx >> 11;
        int valid = ((idx & (MSEL - 1)) < scal[9 + b]) ? 1 : 0;
        int t = valid ? sel[idx] : 0;
        int g = t & 7, tq = t >> 3;
        int lslot = atomicAdd(&lcnt[g], 1);
        __syncthreads();
        if (tid < KJ) lbase[tid] = atomicAdd(&scal[17 + tid], lcnt[tid]);
        __syncthreads();
        groups[g * BI_TOT + lbase[g] + lslot] = (idx << 11) | (tq << 1) | valid;
    } else if (bid < 81) {
        int v = bid - 64;
        float s = blockReduceSum256(b0[tid] * Wl[v * EE + tid]);
        if (tid == 0) bf0[v] = s + bl[v];
    } else {
        int c17 = bid - 81;                          // 0..135
        int j = c17 / V1, v = c17 - j * V1;
        int colP = j * 20 + v;
        float s = blockReduceSum256(b1[tid] * bf2f(wfT[colP * WSTRIDE + tid]));
        if (tid == 0) bias2[colP] = s;
    }
}

// MFMA: wct[g][m=col][e] = sum_em wfT[m][em] * W1[e][em][g]   (A=wfT, B=W1 slice)
// grid 64: (g, e-chunk of 32); 256 thr = 4 waves: wave = (ntile 0/1, mhalf 0/1) -> 5 m-tiles each
__global__ __launch_bounds__(256) void k_wcomb(const float* W1, const unsigned short* wfT,
                                               unsigned short* wct) {
    int g = blockIdx.x >> 3;
    int e0 = (blockIdx.x & 7) * 32;
    __shared__ __align__(16) unsigned short b1s[32 * WSTRIDE];   // [e_local][em]
    __shared__ __align__(16) unsigned short af[NCOLP * 72];      // [m][em-chunk(64)+pad]
    int tid = threadIdx.x;
    {   // stage B (full K): lanes consecutive in em -> 32B-stride reads
        int em_l = tid & 63;
        int eb = (tid >> 6) * 8;
        #pragma unroll
        for (int i = 0; i < 8; ++i) {
            int e = eb + i;
            #pragma unroll
            for (int c = 0; c < 4; ++c) {
                int em = c * 64 + em_l;
                b1s[e * WSTRIDE + em] = f2bf(W1[(e0 + e) * (EE * KJ) + em * KJ + g]);
            }
        }
    }
    for (int idx = tid; idx < 1280; idx += 256) {   // stage A chunk 0 (16B copies)
        int row = idx >> 3, f = idx & 7;
        ((int4*)af)[row * 9 + f] = ((const int4*)wfT)[row * 33 + f];
    }
    __syncthreads();

    int w = tid >> 6, l = tid & 63;
    int ntile = w & 1, mhalf = w >> 1;
    int lr = l & 15, lq = l >> 4;
    f32x4 acc[5];
    #pragma unroll
    for (int t = 0; t < 5; ++t) acc[t] = (f32x4){0.f, 0.f, 0.f, 0.f};

    for (int ch = 0; ch < 4; ++ch) {
        if (ch) {
            __syncthreads();
            for (int idx = tid; idx < 1280; idx += 256) {
                int row = idx >> 3, f = idx & 7;
                ((int4*)af)[row * 9 + f] = ((const int4*)wfT)[row * 33 + ch * 8 + f];
            }
            __syncthreads();
        }
        #pragma unroll
        for (int s = 0; s < 2; ++s) {
            bf16x8 bfr = *(const bf16x8*)&b1s[(ntile * 16 + lr) * WSTRIDE + ch * 64 + s * 32 + lq * 8];
            #pragma unroll
            for (int t = 0; t < 5; ++t) {
                bf16x8 afr = *(const bf16x8*)&af[((mhalf * 5 + t) * 16 + lr) * 72 + s * 32 + lq * 8];
                acc[t] = __builtin_amdgcn_mfma_f32_16x16x32_bf16(afr, bfr, acc[t], 0, 0, 0);
            }
        }
    }
    #pragma unroll
    for (int t = 0; t < 5; ++t) {
        int m = (mhalf * 5 + t) * 16 + lq * 4;       // C/D: row = (l>>4)*4 + reg
        int n = e0 + ntile * 16 + lr;                // C/D: col = l&15
        #pragma unroll
        for (int r = 0; r < 4; ++r)
            wct[(g * NCOLP + m + r) * WSTRIDE + n] = f2bf(acc[t][r]);
    }
}

// Main MFMA grouped GEMM: block = (g, 32-row tile): C[32 x 160] = X[32 x 256] * WcombT^T
// 256 thr = 4 waves: wave = (row-tile 0/1, col-half 0/1) -> 5 col-tiles each. LDS ~40KB.
__global__ __launch_bounds__(256) void k_main(const float* x, const unsigned short* wct,
        const int* scal, const int* groups, const float* bias2, const float* bf0, float* out) {
    int g = blockIdx.x >> 9;
    int tile = blockIdx.x & 511;
    int cntg = scal[17 + g];
    if (tile * 32 >= cntg) return;
    int nrows = min(32, cntg - tile * 32);

    __shared__ __align__(16) unsigned short xs[32 * WSTRIDE];    // [row][e] bf16
    __shared__ __align__(16) unsigned short wts[NCOLP * 72];     // [col][e-chunk(64)+pad]
    __shared__ int xoffs[32], obase[32];
    __shared__ unsigned char vflag[32];

    int tid = threadIdx.x;
    if (tid < 32) {
        int flag = 0, xo = 0, ob = 0;
        if (tid < nrows) {
            int p = groups[g * BI_TOT + tile * 32 + tid];
            int valid = p & 1;
            int tq = (p >> 1) & 1023;
            int bi = p >> 11;
            int b = bi >> 11;
            xo = (b * TC + tq) * EE;
            ob = bi * 136;
            flag = 1 + valid;
        }
        xoffs[tid] = xo; obase[tid] = ob; vflag[tid] = (unsigned char)flag;
    }
    __syncthreads();
    {   // stage x rows f32->bf16: row = tid>>3, 8 float4 each, coalesced per row
        int row = tid >> 3, q = tid & 7;
        const float* xp = x + xoffs[row];
        #pragma unroll
        for (int i = 0; i < 8; ++i) {
            int f4 = q + 8 * i;
            float4 v = *(const float4*)(xp + f4 * 4);
            ushort4 pk;
            pk.x = f2bf(v.x); pk.y = f2bf(v.y); pk.z = f2bf(v.z); pk.w = f2bf(v.w);
            *(ushort4*)&xs[row * WSTRIDE + f4 * 4] = pk;
        }
    }
    const int4* wsrc = (const int4*)wct;
    for (int idx = tid; idx < 1280; idx += 256) {    // stage W chunk 0
        int row = idx >> 3, f = idx & 7;
        ((int4*)wts)[row * 9 + f] = wsrc[(g * NCOLP + row) * 33 + f];
    }
    __syncthreads();

    int w = tid >> 6, l = tid & 63;
    int rw = w & 1, chalf = w >> 1;
    int lr = l & 15, lq = l >> 4;
    f32x4 acc[5];
    #pragma unroll
    for (int t = 0; t < 5; ++t) acc[t] = (f32x4){0.f, 0.f, 0.f, 0.f};

    for (int ch = 0; ch < 4; ++ch) {
        if (ch) {
            __syncthreads();
            for (int idx = tid; idx < 1280; idx += 256) {
                int row = idx >> 3, f = idx & 7;
                ((int4*)wts)[row * 9 + f] = wsrc[(g * NCOLP + row) * 33 + ch * 8 + f];
            }
            __syncthreads();
        }
        #pragma unroll
        for (int s = 0; s < 2; ++s) {
            bf16x8 afr = *(const bf16x8*)&xs[(rw * 16 + lr) * WSTRIDE + ch * 64 + s * 32 + lq * 8];
            #pragma unroll
            for (int t = 0; t < 5; ++t) {
                bf16x8 bfr = *(const bf16x8*)&wts[((chalf * 5 + t) * 16 + lr) * 72 + s * 32 + lq * 8];
                acc[t] = __builtin_amdgcn_mfma_f32_16x16x32_bf16(afr, bfr, acc[t], 0, 0, 0);
            }
        }
    }
    #pragma unroll
    for (int t = 0; t < 5; ++t) {
        int col = (chalf * 5 + t) * 16 + lr;
        int j = col / 20, v = col % 20;
        if (v < V1) {
            float bb = bias2[col] + bf0[v];
            float b0v = bf0[v];
            #pragma unroll
            for (int r = 0; r < 4; ++r) {
                int row = rw * 16 + lq * 4 + r;
                int fl = vflag[row];
                if (fl) out[obase[row] + j * V1 + v] = (fl == 2) ? (acc[t][r] + bb) : b0v;
            }
        }
    }
}

extern "C" void kernel_launch(void* const* d_in, const int* in_sizes, int n_in,
                              void* d_out, int out_size, void* d_ws, size_t ws_size,
                              hipStream_t stream) {
    const float* x     = (const float*)d_in[0];
    const int*   value = (const int*)d_in[1];
    const int*   depth = (const int*)d_in[2];
    // d_in[3] = pos (unused), d_in[4] = num_mix (constant 2048)
    const float* W1    = (const float*)d_in[5];
    const float* b1    = (const float*)d_in[6];
    const float* W0    = (const float*)d_in[7];
    const float* b0    = (const float*)d_in[8];
    const float* Wl    = (const float*)d_in[9];
    const float* bl    = (const float*)d_in[10];
    float* out = (float*)d_out;
    char* ws = (char*)d_ws;

    int*            scal   = (int*)(ws + SCAL_OFF);
    int*            sel    = (int*)(ws + SEL_OFF);
    int*            groups = (int*)(ws + GRP_OFF);
    unsigned short* wfT    = (unsigned short*)(ws + WFT_OFF);
    float*          bias2  = (float*)(ws + B2_OFF);
    float*          bf0    = (float*)(ws + BF0_OFF);
    unsigned short* wct    = (unsigned short*)(ws + WCT_OFF);

    k_maxdepth<<<dim3(192), dim3(256), 0, stream>>>(depth, scal);
    k_len1    <<<dim3(192), dim3(256), 0, stream>>>(depth, scal);
    k_scan    <<<dim3(BB),  dim3(256), 0, stream>>>(value, scal, sel);
    k_wfused  <<<dim3(EE),  dim3(256), 0, stream>>>(W0, Wl, wfT);
    k_grpbias <<<dim3(217), dim3(256), 0, stream>>>(sel, scal, groups, b0, bl, b1, Wl, wfT, bias2, bf0);
    k_wcomb   <<<dim3(64),  dim3(256), 0, stream>>>(W1, wfT, wct);
    k_main    <<<dim3(4096), dim3(256), 0, stream>>>(x, wct, scal, groups, bias2, bf0, out);
}